// Round 6
// baseline (391.447 us; speedup 1.0000x reference)
//
#include <hip/hip_runtime.h>

#define NN 100000
#define NE 1600000
#define F 128
#define CAP 64

// ---------------- build inverted adjacency (fixed-capacity buckets) ----------
__global__ __launch_bounds__(256) void build_k(const int* __restrict__ erow,
                                               const int* __restrict__ ecol,
                                               int* __restrict__ cnt,
                                               int* __restrict__ bucket) {
    int e = blockIdx.x * 256 + threadIdx.x;
    if (e >= NE) return;
    int r = erow[e];
    int pos = atomicAdd(&cnt[r], 1);
    if (pos < CAP) bucket[r * CAP + pos] = ecol[e];
}

// ------------- mean aggregation v2: 32 lanes per node, float4 gathers --------
__global__ __launch_bounds__(256) void agg_k(const float* __restrict__ x,
                                             const int* __restrict__ cnt,
                                             const int* __restrict__ bucket,
                                             float* __restrict__ agg) {
    const int grp  = threadIdx.x >> 5;           // 8 groups of 32 lanes per block
    const int node = blockIdx.x * 8 + grp;
    const int gl   = threadIdx.x & 31;
    if (node >= NN) return;
    const int c = cnt[node];
    const int m = c < CAP ? c : CAP;
    // preload neighbor list into the group's registers (coalesced 128B x2)
    const int idx0 = (gl < m)      ? bucket[node * CAP + gl]      : 0;
    const int idx1 = (32 + gl < m) ? bucket[node * CAP + 32 + gl] : 0;

    float sx = 0.f, sy = 0.f, sz = 0.f, sw = 0.f;
    int k = 0;
    for (; k + 4 <= m; k += 4) {
        int i0 = __shfl((k + 0) < 32 ? idx0 : idx1, (k + 0) & 31, 32);
        int i1 = __shfl((k + 1) < 32 ? idx0 : idx1, (k + 1) & 31, 32);
        int i2 = __shfl((k + 2) < 32 ? idx0 : idx1, (k + 2) & 31, 32);
        int i3 = __shfl((k + 3) < 32 ? idx0 : idx1, (k + 3) & 31, 32);
        float4 v0 = *(const float4*)(x + (size_t)i0 * F + gl * 4);
        float4 v1 = *(const float4*)(x + (size_t)i1 * F + gl * 4);
        float4 v2 = *(const float4*)(x + (size_t)i2 * F + gl * 4);
        float4 v3 = *(const float4*)(x + (size_t)i3 * F + gl * 4);
        sx += v0.x + v1.x + v2.x + v3.x;
        sy += v0.y + v1.y + v2.y + v3.y;
        sz += v0.z + v1.z + v2.z + v3.z;
        sw += v0.w + v1.w + v2.w + v3.w;
    }
    for (; k < m; ++k) {
        int ii = __shfl(k < 32 ? idx0 : idx1, k & 31, 32);
        float4 v = *(const float4*)(x + (size_t)ii * F + gl * 4);
        sx += v.x; sy += v.y; sz += v.z; sw += v.w;
    }
    const float inv = 1.f / (float)(c > 1 ? c : 1);
    float4 r;
    r.x = sx * inv; r.y = sy * inv; r.z = sz * inv; r.w = sw * inv;
    *(float4*)(agg + (size_t)node * F + gl * 4) = r;
}

// --- fp32 GEMM v3: 1024 threads, 128x128 tile, A streamed (16-lane bcast) ---
// sW 64KB -> 2 blocks/CU -> 32 waves/CU (8/SIMD). + bias, deg0-mask, L2norm.
#define BM 128

__global__ __launch_bounds__(1024) void gemm_k(const float* __restrict__ A,
                                               const float* __restrict__ W,
                                               const float* __restrict__ b,
                                               const int* __restrict__ cnt,
                                               float* __restrict__ out) {
    __shared__ float sW[128 * 128];   // 64 KB
    const int tid = threadIdx.x;
    const int base = blockIdx.x * BM;

    // stage W (128 x 128), coalesced float4: 1024 threads x 4
    #pragma unroll
    for (int i = 0; i < 4; ++i) {
        int idx = tid + i * 1024;
        int r = idx >> 5, c4 = idx & 31;
        *(float4*)&sW[r * 128 + c4 * 4] = *(const float4*)(W + r * F + c4 * 4);
    }
    __syncthreads();

    const int tc = tid & 15;   // owns cols tc*8 .. tc*8+7
    const int tr = tid >> 4;   // 0..63: owns rows tr, tr+64 (16 lanes/row bcast)

    const float* arow[2];
    #pragma unroll
    for (int i = 0; i < 2; ++i) {
        int row = base + tr + 64 * i;
        int rowc = row < NN ? row : NN - 1;   // clamp; store is masked
        arow[i] = A + (size_t)rowc * F;
    }

    float acc[2][8];
    #pragma unroll
    for (int i = 0; i < 2; ++i)
        #pragma unroll
        for (int j = 0; j < 8; ++j) acc[i][j] = 0.f;

    #pragma unroll 4
    for (int k4 = 0; k4 < 32; ++k4) {
        float4 a4[2];
        #pragma unroll
        for (int i = 0; i < 2; ++i)
            a4[i] = *(const float4*)(arow[i] + k4 * 4);   // global bcast load
        #pragma unroll
        for (int kk = 0; kk < 4; ++kk) {
            int k = k4 * 4 + kk;
            float4 w0 = *(const float4*)&sW[k * 128 + tc * 8];
            float4 w1 = *(const float4*)&sW[k * 128 + tc * 8 + 4];
            float w[8] = {w0.x, w0.y, w0.z, w0.w, w1.x, w1.y, w1.z, w1.w};
            #pragma unroll
            for (int i = 0; i < 2; ++i) {
                const float* ap = (const float*)&a4[i];   // kk unrolled: static idx
                float av = ap[kk];
                #pragma unroll
                for (int j = 0; j < 8; ++j)
                    acc[i][j] = fmaf(av, w[j], acc[i][j]);
            }
        }
    }

    // epilogue: bias (deg>0 only), row L2-normalize, store
    float4 b0 = *(const float4*)(b + tc * 8);
    float4 b1 = *(const float4*)(b + tc * 8 + 4);
    float bb[8] = {b0.x, b0.y, b0.z, b0.w, b1.x, b1.y, b1.z, b1.w};
    #pragma unroll
    for (int i = 0; i < 2; ++i) {
        int row = base + tr + 64 * i;
        bool valid = row < NN;
        int deg = valid ? cnt[row] : 0;
        float v[8];
        float sumsq = 0.f;
        #pragma unroll
        for (int j = 0; j < 8; ++j) {
            float t = (deg > 0) ? (acc[i][j] + bb[j]) : 0.f;
            v[j] = t;
            sumsq += t * t;
        }
        // the 16 threads sharing tr are consecutive lanes -> xor-reduce
        #pragma unroll
        for (int off = 1; off < 16; off <<= 1)
            sumsq += __shfl_xor(sumsq, off);
        float nrm = fmaxf(sqrtf(sumsq), 1e-12f);
        float s = 1.f / nrm;
        if (valid) {
            float4 o0 = make_float4(v[0] * s, v[1] * s, v[2] * s, v[3] * s);
            float4 o1 = make_float4(v[4] * s, v[5] * s, v[6] * s, v[7] * s);
            *(float4*)(out + (size_t)row * F + tc * 8) = o0;
            *(float4*)(out + (size_t)row * F + tc * 8 + 4) = o1;
        }
    }
}

extern "C" void kernel_launch(void* const* d_in, const int* in_sizes, int n_in,
                              void* d_out, int out_size, void* d_ws, size_t ws_size,
                              hipStream_t stream) {
    const float* x    = (const float*)d_in[0];
    const int*   erow = (const int*)d_in[1];
    const int*   ecol = (const int*)d_in[2];
    const float* W    = (const float*)d_in[3];
    const float* b    = (const float*)d_in[4];
    float* out = (float*)d_out;

    // workspace layout: agg [NN*F f32] | cnt [NN i32] | bucket [NN*CAP i32]
    float* agg    = (float*)d_ws;
    int*   cnt    = (int*)(agg + (size_t)NN * F);
    int*   bucket = cnt + NN;

    hipMemsetAsync(cnt, 0, NN * sizeof(int), stream);
    build_k<<<(NE + 255) / 256, 256, 0, stream>>>(erow, ecol, cnt, bucket);
    agg_k<<<(NN + 7) / 8, 256, 0, stream>>>(x, cnt, bucket, agg);
    gemm_k<<<(NN + BM - 1) / BM, BM * 8, 0, stream>>>(agg, W, b, cnt, out);
}